// Round 3
// baseline (59.404 us; speedup 1.0000x reference)
//
#include <hip/hip_runtime.h>

#define S 256
#define NF 4096
#define TILE 16
#define NTILES ((S / TILE) * (S / TILE))   // 256
#define CAP 1024                           // slots per tile (avg occupancy ~41)
#define NT2 1024                           // render threads: 4 slices x 256 pixels
#define SLICES 4
#define NEARF 0.1f
#define FARF 100.0f
#define EPSF 1e-8f

// ws layout: [0, 1024)            tile_count[256] (int)
//            [4096, 4096+12.6MB)  tile_data[256][CAP][3] (float4, 48B/slot)
#define WS_DATA_OFF 4096

// ---------------- Kernel 1: bin faces into per-tile lists ----------------
// 16 blocks x 256 threads. Faces staged into LDS coalesced (stride-256 dword
// loads), then each thread culls exactly one face (single pass over the scene,
// vs 256x redundant per-tile culling) and scatters an aligned 48B record.
__global__ __launch_bounds__(256) void bin_faces(const float* __restrict__ faces,
                                                 int* __restrict__ tile_count,
                                                 float4* __restrict__ tile_data) {
    __shared__ float s_f[256 * 9];
    const int base = blockIdx.x * 256;
    // coalesced stage: 9 x stride-256 dword loads
    for (int k = threadIdx.x; k < 256 * 9; k += 256)
        s_f[k] = faces[base * 9 + k];
    __syncthreads();

    const int t = threadIdx.x;
    const float* p = s_f + t * 9;           // 9t mod 32: 9 coprime 32 -> 2-way max (free)
    const float x0 = p[0], y0 = p[1], z0 = p[2];
    const float x1 = p[3], y1 = p[4], z1 = p[5];
    const float x2 = p[6], y2 = p[7], z2 = p[8];

    // Backface cull in double: w_sum noise in fp32 is ~1e-6 << 1e-4 margin.
    const double a2 = ((double)x1 - (double)x0) * ((double)y2 - (double)y0) -
                      ((double)x2 - (double)x0) * ((double)y1 - (double)y0);
    if (a2 <= -1e-4) return;

    const float bxmin = fminf(x0, fminf(x1, x2)) - 1e-3f;
    const float bxmax = fmaxf(x0, fmaxf(x1, x2)) + 1e-3f;
    const float bymin = fminf(y0, fminf(y1, y2)) - 1e-3f;
    const float bymax = fmaxf(y0, fmaxf(y1, y2)) + 1e-3f;

    // xp(px) = (2px+1-256)/256  =>  px = (256*xp + 255)/2. Extra +-1 px slack
    // makes the pixel range a strict superset of any fp32 inside-test flip.
    int pxlo = (int)ceilf((256.0f * bxmin + 255.0f) * 0.5f) - 1;
    int pxhi = (int)floorf((256.0f * bxmax + 255.0f) * 0.5f) + 1;
    int pylo = (int)ceilf((256.0f * bymin + 255.0f) * 0.5f) - 1;
    int pyhi = (int)floorf((256.0f * bymax + 255.0f) * 0.5f) + 1;
    if (pxhi < 0 || pxlo > S - 1 || pyhi < 0 || pylo > S - 1) return;
    pxlo = pxlo < 0 ? 0 : pxlo;
    pylo = pylo < 0 ? 0 : pylo;
    pxhi = pxhi > S - 1 ? S - 1 : pxhi;
    pyhi = pyhi > S - 1 ? S - 1 : pyhi;

    const int f = base + t;
    const float4 d0 = make_float4(x0, y0, x1, y1);
    const float4 d1 = make_float4(x2, y2, z0, z1);
    const float4 d2 = make_float4(z2, __int_as_float(f), 0.0f, 0.0f);
    for (int ty = pylo >> 4; ty <= pyhi >> 4; ++ty)
        for (int tx = pxlo >> 4; tx <= pxhi >> 4; ++tx) {
            const int tile = ty * (S / TILE) + tx;
            const int slot = atomicAdd(&tile_count[tile], 1);
            if (slot < CAP) {
                float4* dst = tile_data + ((size_t)tile * CAP + slot) * 3;
                dst[0] = d0;
                dst[1] = d1;
                dst[2] = d2;
            }
        }
}

// ---------------- Kernel 2: render one tile per block ----------------
// 4 threads per pixel scan disjoint quarters of the tile list with 1-ahead
// prefetch; bit-exact fp32 math (no fma, IEEE div, exact association); merge
// via (depth_bits<<32 | face) min-key -> order-independent, implements the
// lowest-index-at-equal-depth tie-break exactly.
__global__ __launch_bounds__(NT2) void render_tiles(const int* __restrict__ tile_count,
                                                    const float4* __restrict__ tile_data,
                                                    int* __restrict__ out) {
    __shared__ unsigned long long s_key[NT2];

    const int tile = blockIdx.x;
    const int tx0 = (tile & (S / TILE - 1)) * TILE;
    const int ty0 = (tile / (S / TILE)) * TILE;

    int n = tile_count[tile];
    n = n < CAP ? n : CAP;

    const int pix = threadIdx.x & 255;
    const int slice = threadIdx.x >> 8;      // wave-uniform
    const int px = tx0 + (pix & (TILE - 1));
    const int py = ty0 + (pix / TILE);
    // (2i+1-256)/256: odd numerator / pow2 -> exact in fp32.
    const float xp = (2.0f * px + 1.0f - 256.0f) * (1.0f / 256.0f);
    const float yp = (2.0f * py + 1.0f - 256.0f) * (1.0f / 256.0f);

    float bestd = FARF;
    int bestf = 0x7fffffff;

    const float4* td = tile_data + (size_t)tile * CAP * 3;
    int i = slice;
    float4 A, B, C;
    if (i < n) {
        A = td[i * 3 + 0];
        B = td[i * 3 + 1];
        C = td[i * 3 + 2];
    }
    while (i < n) {
        const int j = i + SLICES;
        float4 An, Bn, Cn;
        if (j < n) {                          // prefetch next before compute
            An = td[j * 3 + 0];
            Bn = td[j * 3 + 1];
            Cn = td[j * 3 + 2];
        }
        {
            const float X0 = A.x, Y0 = A.y, Z0 = B.z;
            const float X1 = A.z, Y1 = A.w, Z1 = B.w;
            const float X2 = B.x, Y2 = B.y, Z2 = C.x;
            const int f = __float_as_int(C.y);
            const float w0 = __fsub_rn(__fmul_rn(__fsub_rn(yp, Y1), __fsub_rn(X2, X1)),
                                       __fmul_rn(__fsub_rn(xp, X1), __fsub_rn(Y2, Y1)));
            const float w1 = __fsub_rn(__fmul_rn(__fsub_rn(yp, Y2), __fsub_rn(X0, X2)),
                                       __fmul_rn(__fsub_rn(xp, X2), __fsub_rn(Y0, Y2)));
            const float w2 = __fsub_rn(__fmul_rn(__fsub_rn(yp, Y0), __fsub_rn(X1, X0)),
                                       __fmul_rn(__fsub_rn(xp, X0), __fsub_rn(Y1, Y0)));
            const bool inside = (__fmul_rn(w0, w1) > 0.0f) && (__fmul_rn(w1, w2) > 0.0f);
            const float wsum = __fadd_rn(__fadd_rn(w0, w1), w2);
            if (inside && (wsum > 0.0f)) {
                float denom = __fadd_rn(__fadd_rn(__fdiv_rn(w0, Z0), __fdiv_rn(w1, Z1)),
                                        __fdiv_rn(w2, Z2));
                denom = (fabsf(denom) > EPSF) ? denom : EPSF;
                const float zp = __fdiv_rn(wsum, denom);
                if ((zp > NEARF) && (zp < FARF)) {
                    if (zp < bestd || (zp == bestd && f < bestf)) {
                        bestd = zp;
                        bestf = f;
                    }
                }
            }
        }
        i = j;
        A = An;
        B = Bn;
        C = Cn;
    }

    s_key[threadIdx.x] =
        ((unsigned long long)__float_as_uint(bestd) << 32) | (unsigned int)bestf;
    __syncthreads();
    if (threadIdx.x < 256) {
        unsigned long long k = s_key[threadIdx.x];
        unsigned long long k1 = s_key[threadIdx.x + 256];
        unsigned long long k2 = s_key[threadIdx.x + 512];
        unsigned long long k3 = s_key[threadIdx.x + 768];
        k = k1 < k ? k1 : k;
        k = k2 < k ? k2 : k;
        k = k3 < k ? k3 : k;
        const float d = __uint_as_float((unsigned int)(k >> 32));
        const int fi = (int)(unsigned int)k;
        const int opx = tx0 + (threadIdx.x & (TILE - 1));
        const int opy = ty0 + (threadIdx.x / TILE);
        out[opy * S + opx] = (d < FARF) ? fi : -1;
    }
}

extern "C" void kernel_launch(void* const* d_in, const int* in_sizes, int n_in,
                              void* d_out, int out_size, void* d_ws, size_t ws_size,
                              hipStream_t stream) {
    const float* faces = (const float*)d_in[0];
    int* out = (int*)d_out;
    int* tile_count = (int*)d_ws;
    float4* tile_data = (float4*)((char*)d_ws + WS_DATA_OFF);

    hipMemsetAsync(tile_count, 0, NTILES * sizeof(int), stream);
    hipLaunchKernelGGL(bin_faces, dim3(NF / 256), dim3(256), 0, stream,
                       faces, tile_count, tile_data);
    hipLaunchKernelGGL(render_tiles, dim3(NTILES), dim3(NT2), 0, stream,
                       tile_count, tile_data, out);
}

// Round 4
// 33.562 us; speedup vs baseline: 1.7700x; 1.7700x over previous
//
#include <hip/hip_runtime.h>

#define S 256
#define NF 4096
#define TILE 16
#define NT 1024            // 4 slices x 256 pixels
#define SLICES 4
#define CHUNKF 1024        // faces per staged chunk (== NT)
#define NCHUNK (NF / CHUNKF)
#define CAPC 256           // candidate slots per chunk (avg ~10 used)
#define NEARF 0.1f
#define FARF 100.0f
#define EPSF 1e-8f

// One block per 16x16 tile, 1024 threads. Per 1024-face chunk:
//   stage:  coalesced float4 global->LDS (kills the 36B-stride scattered-load
//           pattern that made round 2 texture-pipe bound: ~16 lines/instr
//           instead of ~36 lines/instr x 9 instrs per face)
//   cull:   thread t tests face t (bbox vs tile + double-prec backface, both
//           conservative) and compacts survivors into an LDS candidate list
//   render: 4 threads/pixel scan the candidates (broadcast ds_read_b128),
//           bit-exact __f*_rn math; merge via (depth_bits<<32|face) min-key,
//           order-independent and implementing the exact lowest-index tie-break.
// Overflow (>CAPC candidates in a chunk): render tests the whole chunk directly;
// the cull is conservative, so skipping it cannot change any pixel's result.
__global__ __launch_bounds__(NT) void raster_tile(const float* __restrict__ faces,
                                                  int* __restrict__ out) {
    __shared__ float4 s_face[CHUNKF * 9 / 4];   // 36 KB
    __shared__ float4 s_cand[CAPC][3];          // 12 KB
    __shared__ unsigned long long s_key[NT];    // 8 KB
    __shared__ int s_cnt;

    const float* s_face_f = (const float*)s_face;

    const int tile = blockIdx.x;
    const int tx0 = (tile & (S / TILE - 1)) * TILE;
    const int ty0 = (tile / (S / TILE)) * TILE;

    const int pix = threadIdx.x & 255;
    const int slice = threadIdx.x >> 8;          // wave-uniform
    const int px = tx0 + (pix & (TILE - 1));
    const int py = ty0 + (pix / TILE);
    // (2i+1-256)/256: odd numerator / pow2 -> exact in fp32.
    const float xp = (2.0f * px + 1.0f - 256.0f) * (1.0f / 256.0f);
    const float yp = (2.0f * py + 1.0f - 256.0f) * (1.0f / 256.0f);

    // Tile pixel-center bounds with margin vs ulp-level boundary flips.
    const float cxlo = (2.0f * tx0 + 1.0f - 256.0f) * (1.0f / 256.0f) - 1e-5f;
    const float cxhi = (2.0f * (tx0 + TILE - 1) + 1.0f - 256.0f) * (1.0f / 256.0f) + 1e-5f;
    const float cylo = (2.0f * ty0 + 1.0f - 256.0f) * (1.0f / 256.0f) - 1e-5f;
    const float cyhi = (2.0f * (ty0 + TILE - 1) + 1.0f - 256.0f) * (1.0f / 256.0f) + 1e-5f;

    float bestd = FARF;
    int bestf = 0x7fffffff;

#define BODY(X0, Y0, Z0, X1, Y1, Z1, X2, Y2, Z2, FIDX)                                   \
    {                                                                                    \
        const float w0 = __fsub_rn(__fmul_rn(__fsub_rn(yp, Y1), __fsub_rn(X2, X1)),      \
                                   __fmul_rn(__fsub_rn(xp, X1), __fsub_rn(Y2, Y1)));     \
        const float w1 = __fsub_rn(__fmul_rn(__fsub_rn(yp, Y2), __fsub_rn(X0, X2)),      \
                                   __fmul_rn(__fsub_rn(xp, X2), __fsub_rn(Y0, Y2)));     \
        const float w2 = __fsub_rn(__fmul_rn(__fsub_rn(yp, Y0), __fsub_rn(X1, X0)),      \
                                   __fmul_rn(__fsub_rn(xp, X0), __fsub_rn(Y1, Y0)));     \
        const bool inside = (__fmul_rn(w0, w1) > 0.0f) && (__fmul_rn(w1, w2) > 0.0f);    \
        const float wsum = __fadd_rn(__fadd_rn(w0, w1), w2);                             \
        if (inside && (wsum > 0.0f)) {                                                   \
            float denom = __fadd_rn(__fadd_rn(__fdiv_rn(w0, Z0), __fdiv_rn(w1, Z1)),     \
                                    __fdiv_rn(w2, Z2));                                  \
            denom = (fabsf(denom) > EPSF) ? denom : EPSF;                                \
            const float zp = __fdiv_rn(wsum, denom);                                     \
            if ((zp > NEARF) && (zp < FARF)) {                                           \
                if (zp < bestd || (zp == bestd && (FIDX) < bestf)) {                     \
                    bestd = zp;                                                          \
                    bestf = (FIDX);                                                      \
                }                                                                        \
            }                                                                            \
        }                                                                                \
    }

    for (int c = 0; c < NCHUNK; ++c) {
        __syncthreads();   // s_face / s_cand / s_cnt free for reuse

        // ---- stage: coalesced float4 global -> LDS ----
        const float4* gsrc = (const float4*)faces + (size_t)c * (CHUNKF * 9 / 4);
        for (int k = threadIdx.x; k < CHUNKF * 9 / 4; k += NT)
            s_face[k] = gsrc[k];
        if (threadIdx.x == 0) s_cnt = 0;
        __syncthreads();

        // ---- cull: one face per thread, from LDS ----
        {
            const float* p = s_face_f + threadIdx.x * 9;   // 9 coprime 32 -> <=2-way, free
            const float x0 = p[0], y0 = p[1], z0 = p[2];
            const float x1 = p[3], y1 = p[4], z1 = p[5];
            const float x2 = p[6], y2 = p[7], z2 = p[8];
            const float bxmin = fminf(x0, fminf(x1, x2));
            const float bxmax = fmaxf(x0, fmaxf(x1, x2));
            const float bymin = fminf(y0, fminf(y1, y2));
            const float bymax = fmaxf(y0, fmaxf(y1, y2));
            bool hit = (bxmax >= cxlo) && (bxmin <= cxhi) &&
                       (bymax >= cylo) && (bymin <= cyhi);
            if (hit) {
                // 2*signed area in double; fp32 w_sum noise ~1e-6 << 1e-4 margin,
                // so no pixel whose fp32 w_sum>0 can be culled.
                const double a2 = ((double)x1 - (double)x0) * ((double)y2 - (double)y0) -
                                  ((double)x2 - (double)x0) * ((double)y1 - (double)y0);
                hit = (a2 > -1e-4);
            }
            if (hit) {
                const int slot = atomicAdd(&s_cnt, 1);
                if (slot < CAPC) {
                    s_cand[slot][0] = make_float4(x0, y0, x1, y1);
                    s_cand[slot][1] = make_float4(x2, y2, z0, z1);
                    s_cand[slot][2] =
                        make_float4(z2, __int_as_float(c * CHUNKF + threadIdx.x), 0.0f, 0.0f);
                }
            }
        }
        __syncthreads();

        // ---- render: sliced scan of this chunk's candidates ----
        const int n = s_cnt;
        if (n <= CAPC) {
            for (int i = slice; i < n; i += SLICES) {
                const float4 d0 = s_cand[i][0];   // broadcast reads, conflict-free
                const float4 d1 = s_cand[i][1];
                const float4 d2 = s_cand[i][2];
                const int f = __float_as_int(d2.y);
                BODY(d0.x, d0.y, d1.z, d0.z, d0.w, d1.w, d1.x, d1.y, d2.x, f)
            }
        } else {
            // Overflow: test every face of the chunk directly (conservative-cull
            // equivalence keeps this exact). Statistically never taken.
            for (int i = slice; i < CHUNKF; i += SLICES) {
                const float* p = s_face_f + i * 9;
                BODY(p[0], p[1], p[2], p[3], p[4], p[5], p[6], p[7], p[8], c * CHUNKF + i)
            }
        }
    }
#undef BODY

    // ---- merge 4 slices per pixel via packed min-key ----
    s_key[threadIdx.x] =
        ((unsigned long long)__float_as_uint(bestd) << 32) | (unsigned int)bestf;
    __syncthreads();
    if (threadIdx.x < 256) {
        unsigned long long k = s_key[threadIdx.x];
        unsigned long long k1 = s_key[threadIdx.x + 256];
        unsigned long long k2 = s_key[threadIdx.x + 512];
        unsigned long long k3 = s_key[threadIdx.x + 768];
        k = k1 < k ? k1 : k;
        k = k2 < k ? k2 : k;
        k = k3 < k ? k3 : k;
        const float d = __uint_as_float((unsigned int)(k >> 32));
        const int fi = (int)(unsigned int)k;
        const int opx = tx0 + (threadIdx.x & (TILE - 1));
        const int opy = ty0 + (threadIdx.x / TILE);
        out[opy * S + opx] = (d < FARF) ? fi : -1;
    }
}

extern "C" void kernel_launch(void* const* d_in, const int* in_sizes, int n_in,
                              void* d_out, int out_size, void* d_ws, size_t ws_size,
                              hipStream_t stream) {
    const float* faces = (const float*)d_in[0];
    int* out = (int*)d_out;
    hipLaunchKernelGGL(raster_tile, dim3((S / TILE) * (S / TILE)), dim3(NT), 0, stream,
                       faces, out);
}

// Round 5
// 32.294 us; speedup vs baseline: 1.8395x; 1.0393x over previous
//
#include <hip/hip_runtime.h>

#define S 256
#define NF 4096
#define TILE 16
#define NT 1024            // 4 slices x 256 pixels
#define SLICES 4
#define CAPC 512           // candidate slots (avg ~40 used; overflow -> exact fallback)
#define NEARF 0.1f
#define FARF 100.0f
#define EPSF 1e-8f

// One block per 16x16 tile, 1024 threads, 2 barriers total.
// Round-1 rocprof showed VGPR_Count=16: the compiler's occupancy-first register
// allocation serialized every load (load->waitcnt->consume->reuse). This round:
// __launch_bounds__(NT,4) documents the true residency (4 waves/EU) and raises
// the VGPR cap to 128; cull loads are batched up-front into registers (float4
// pairs, 3 instrs/face instead of 9); the render loop software-pipelines its
// LDS reads 1 ahead. Math is bit-exact __f*_rn as before; candidate order is
// irrelevant due to the (depth_bits<<32|face) min-key merge.
__global__ __launch_bounds__(NT, 4) void raster_tile(const float* __restrict__ faces,
                                                     int* __restrict__ out) {
    __shared__ float4 s_cand[CAPC][3];          // 24 KB
    __shared__ unsigned long long s_key[NT];    // 8 KB
    __shared__ int s_cnt;

    const int tile = blockIdx.x;
    const int tx0 = (tile & (S / TILE - 1)) * TILE;
    const int ty0 = (tile / (S / TILE)) * TILE;

    const int pix = threadIdx.x & 255;
    const int slice = threadIdx.x >> 8;          // wave-uniform
    const int px = tx0 + (pix & (TILE - 1));
    const int py = ty0 + (pix / TILE);
    // (2i+1-256)/256: odd numerator / pow2 -> exact in fp32.
    const float xp = (2.0f * px + 1.0f - 256.0f) * (1.0f / 256.0f);
    const float yp = (2.0f * py + 1.0f - 256.0f) * (1.0f / 256.0f);

    // Tile pixel-center bounds with margin vs ulp-level boundary flips
    // (|w| ~1e-6 flip band corresponds to ~5e-6 NDC; margin 1e-5 covers it).
    const float cxlo = (2.0f * tx0 + 1.0f - 256.0f) * (1.0f / 256.0f) - 1e-5f;
    const float cxhi = (2.0f * (tx0 + TILE - 1) + 1.0f - 256.0f) * (1.0f / 256.0f) + 1e-5f;
    const float cylo = (2.0f * ty0 + 1.0f - 256.0f) * (1.0f / 256.0f) - 1e-5f;
    const float cyhi = (2.0f * (ty0 + TILE - 1) + 1.0f - 256.0f) * (1.0f / 256.0f) + 1e-5f;

    // ---- cull: 4 faces/thread, all 12 loads issued before any use ----
    // Layout per face f (floats at f*9): A=(x0,y0,z0,x1) B=(y1,z1,x2,y2) Cz=z2.
    // f*36B is dword-aligned; gfx950 global loads support dword-aligned dwordx4.
    float4 A[4], B[4];
    float Cz[4];
#pragma unroll
    for (int i = 0; i < 4; ++i) {
        const float* p = faces + (size_t)(i * NT + threadIdx.x) * 9;
        A[i] = *(const float4*)p;
        B[i] = *(const float4*)(p + 4);
        Cz[i] = p[8];
    }
    if (threadIdx.x == 0) s_cnt = 0;
    __syncthreads();   // cheap; sits under the global-load latency

#pragma unroll
    for (int i = 0; i < 4; ++i) {
        const float x0 = A[i].x, y0 = A[i].y, z0 = A[i].z, x1 = A[i].w;
        const float y1 = B[i].x, z1 = B[i].y, x2 = B[i].z, y2 = B[i].w;
        const float z2 = Cz[i];
        const float bxmin = fminf(x0, fminf(x1, x2));
        const float bxmax = fmaxf(x0, fmaxf(x1, x2));
        const float bymin = fminf(y0, fminf(y1, y2));
        const float bymax = fmaxf(y0, fmaxf(y1, y2));
        bool hit = (bxmax >= cxlo) && (bxmin <= cxhi) &&
                   (bymax >= cylo) && (bymin <= cyhi);
        if (hit) {
            // 2*signed area in double; fp32 w_sum noise ~1e-6 << 1e-4 margin,
            // so no pixel whose fp32 w_sum>0 can be culled.
            const double a2 = ((double)x1 - (double)x0) * ((double)y2 - (double)y0) -
                              ((double)x2 - (double)x0) * ((double)y1 - (double)y0);
            hit = (a2 > -1e-4);
        }
        if (hit) {
            const int slot = atomicAdd(&s_cnt, 1);
            if (slot < CAPC) {
                s_cand[slot][0] = A[i];
                s_cand[slot][1] = B[i];
                s_cand[slot][2] =
                    make_float4(z2, __int_as_float(i * NT + (int)threadIdx.x), 0.0f, 0.0f);
            }
        }
    }
    __syncthreads();

    float bestd = FARF;
    int bestf = 0x7fffffff;

#define BODY(X0, Y0, Z0, X1, Y1, Z1, X2, Y2, Z2, FIDX)                                   \
    {                                                                                    \
        const float w0 = __fsub_rn(__fmul_rn(__fsub_rn(yp, Y1), __fsub_rn(X2, X1)),      \
                                   __fmul_rn(__fsub_rn(xp, X1), __fsub_rn(Y2, Y1)));     \
        const float w1 = __fsub_rn(__fmul_rn(__fsub_rn(yp, Y2), __fsub_rn(X0, X2)),      \
                                   __fmul_rn(__fsub_rn(xp, X2), __fsub_rn(Y0, Y2)));     \
        const float w2 = __fsub_rn(__fmul_rn(__fsub_rn(yp, Y0), __fsub_rn(X1, X0)),      \
                                   __fmul_rn(__fsub_rn(xp, X0), __fsub_rn(Y1, Y0)));     \
        const bool inside = (__fmul_rn(w0, w1) > 0.0f) && (__fmul_rn(w1, w2) > 0.0f);    \
        const float wsum = __fadd_rn(__fadd_rn(w0, w1), w2);                             \
        if (inside && (wsum > 0.0f)) {                                                   \
            float denom = __fadd_rn(__fadd_rn(__fdiv_rn(w0, Z0), __fdiv_rn(w1, Z1)),     \
                                    __fdiv_rn(w2, Z2));                                  \
            denom = (fabsf(denom) > EPSF) ? denom : EPSF;                                \
            const float zp = __fdiv_rn(wsum, denom);                                     \
            if ((zp > NEARF) && (zp < FARF)) {                                           \
                if (zp < bestd || (zp == bestd && (FIDX) < bestf)) {                     \
                    bestd = zp;                                                          \
                    bestf = (FIDX);                                                     \
                }                                                                        \
            }                                                                            \
        }                                                                                \
    }

    const int n = s_cnt;
    if (n <= CAPC) {
        // ---- render: sliced scan with 1-ahead LDS prefetch ----
        const int nm1 = n - 1;
        int i = slice;
        float4 a, b, c;
        if (i < n) {
            a = s_cand[i][0];
            b = s_cand[i][1];
            c = s_cand[i][2];
        }
        while (i < n) {
            const int j = i + SLICES;
            const int jc = j <= nm1 ? j : nm1;     // clamped prefetch, no branch
            const float4 an = s_cand[jc][0];
            const float4 bn = s_cand[jc][1];
            const float4 cn = s_cand[jc][2];
            BODY(a.x, a.y, a.z, a.w, b.x, b.y, b.z, b.w, c.x, __float_as_int(c.y))
            i = j;
            a = an;
            b = bn;
            c = cn;
        }
    } else {
        // Overflow (never expected): test every face directly from global.
        // Conservative-cull equivalence keeps this exact.
        for (int i = slice; i < NF; i += SLICES) {
            const float* p = faces + (size_t)i * 9;
            BODY(p[0], p[1], p[2], p[3], p[4], p[5], p[6], p[7], p[8], i)
        }
    }
#undef BODY

    // ---- merge 4 slices per pixel via packed min-key ----
    s_key[threadIdx.x] =
        ((unsigned long long)__float_as_uint(bestd) << 32) | (unsigned int)bestf;
    __syncthreads();
    if (threadIdx.x < 256) {
        unsigned long long k = s_key[threadIdx.x];
        const unsigned long long k1 = s_key[threadIdx.x + 256];
        const unsigned long long k2 = s_key[threadIdx.x + 512];
        const unsigned long long k3 = s_key[threadIdx.x + 768];
        k = k1 < k ? k1 : k;
        k = k2 < k ? k2 : k;
        k = k3 < k ? k3 : k;
        const float d = __uint_as_float((unsigned int)(k >> 32));
        const int fi = (int)(unsigned int)k;
        const int opx = tx0 + (threadIdx.x & (TILE - 1));
        const int opy = ty0 + (threadIdx.x / TILE);
        out[opy * S + opx] = (d < FARF) ? fi : -1;
    }
}

extern "C" void kernel_launch(void* const* d_in, const int* in_sizes, int n_in,
                              void* d_out, int out_size, void* d_ws, size_t ws_size,
                              hipStream_t stream) {
    const float* faces = (const float*)d_in[0];
    int* out = (int*)d_out;
    hipLaunchKernelGGL(raster_tile, dim3((S / TILE) * (S / TILE)), dim3(NT), 0, stream,
                       faces, out);
}